// Round 4
// baseline (138.429 us; speedup 1.0000x reference)
//
#include <hip/hip_runtime.h>
#include <hip/hip_bf16.h>

// Problem constants
#define PN 4096
#define IN 256
#define HN 64
#define AN 32

// Output layout (FLOAT32 elements), concatenated in reference return order:
// response_mu (P*I), ability_mu (P*A), ability_logvar (P*A), item_mu (I), item_logvar (I)
#define OFF_RESP 0
#define OFF_AMU  (PN * IN)                 // 1048576
#define OFF_ALV  (OFF_AMU + PN * AN)       // 1179648
#define OFF_IMU  (OFF_ALV + PN * AN)       // 1310720
#define OFF_ILV  (OFF_IMU + IN)            // 1310976

typedef short  s16x8  __attribute__((ext_vector_type(8)));   // 8 bf16 bit-patterns (guide-exact frag type)
typedef float  f32x4  __attribute__((ext_vector_type(4)));
typedef unsigned short us8v __attribute__((ext_vector_type(8)));

// round-to-nearest-even f32 -> bf16 bits
__device__ __forceinline__ unsigned short f2bf(float f) {
    union { float f; unsigned int u; } v; v.f = f;
    unsigned int u = v.u;
    u += 0x7FFFu + ((u >> 16) & 1u);
    return (unsigned short)(u >> 16);
}

__device__ __forceinline__ float eluf(float x) {
    return x > 0.0f ? x : (__expf(x) - 1.0f);
}

// ---------------------------------------------------------------------------
// Stage 1: per person p, compute hid_mean[p][64] =
//   sum_i mask[p,i] * elu( elu(x[p,i]*w1 + b1) @ w2 + b2 ) / max(sum_i mask, 1)
// One block = one person, 256 threads (4 waves). MFMA over 256x64, K=64.
// Inputs are FLOAT32; we convert h1 and w2 to bf16 for the MFMA path.
// ---------------------------------------------------------------------------
__global__ __launch_bounds__(256, 2) void k_stage1(
    const float* __restrict__ response,
    const int* __restrict__ mask,
    const float* __restrict__ w1,
    const float* __restrict__ b1,
    const float* __restrict__ w2,
    const float* __restrict__ b2,
    float* __restrict__ hid_mean)
{
    // stride 72 ushorts = 144 B (16B aligned rows)
    __shared__ __align__(16) unsigned short sH1[256][72];
    __shared__ __align__(16) unsigned short sW2T[64][72];   // sW2T[n][k] = bf16(w2[k][n])
    __shared__ float sW1[64], sB1[64], sB2[64];
    __shared__ float sM[256];
    __shared__ float sMsum[4];
    __shared__ float sPart[4][64];

    const int t = threadIdx.x;
    const int p = blockIdx.x;
    const int wave = t >> 6;
    const int lane = t & 63;
    const int quad = lane >> 4;
    const int r    = lane & 15;

    // ---- phase 1: stage weights + mask ----
    if (t < 64) {
        sW1[t] = w1[t];
        sB1[t] = b1[t];
        sB2[t] = b2[t];
    }
    for (int idx = t; idx < 4096; idx += 256) {
        int j = idx >> 6, n = idx & 63;       // idx = j*64 + n ; w2[j][n]
        sW2T[n][j] = f2bf(w2[idx]);
    }
    float x = response[p * IN + t];
    float m = (float)mask[p * IN + t];
    sM[t] = m;
    float ms = m;
    #pragma unroll
    for (int off = 32; off; off >>= 1) ms += __shfl_down(ms, off);
    if (lane == 0) sMsum[wave] = ms;
    __syncthreads();

    // ---- phase 2: h1 row for item t: h1[j] = elu(x*w1[j] + b1[j]) -> bf16 LDS ----
    #pragma unroll
    for (int j0 = 0; j0 < 64; j0 += 8) {
        us8v pk;
        #pragma unroll
        for (int u = 0; u < 8; ++u) {
            float a = fmaf(x, sW1[j0 + u], sB1[j0 + u]);
            a = a > 0.0f ? a : (__expf(a) - 1.0f);
            pk[u] = f2bf(a);
        }
        *(us8v*)&sH1[t][j0] = pk;
    }
    __syncthreads();

    // ---- phase 3: MFMA 256x64 @ 64x64 ; wave w covers items [w*64, w*64+64) ----
    f32x4 acc[4][4];
    #pragma unroll
    for (int rt = 0; rt < 4; ++rt)
        #pragma unroll
        for (int ct = 0; ct < 4; ++ct)
            acc[rt][ct] = (f32x4){0.f, 0.f, 0.f, 0.f};

    #pragma unroll
    for (int kk = 0; kk < 64; kk += 32) {
        s16x8 af[4], bfr[4];
        #pragma unroll
        for (int rt = 0; rt < 4; ++rt)
            af[rt] = *(const s16x8*)&sH1[wave * 64 + rt * 16 + r][kk + quad * 8];
        #pragma unroll
        for (int ct = 0; ct < 4; ++ct)
            bfr[ct] = *(const s16x8*)&sW2T[ct * 16 + r][kk + quad * 8];
        #pragma unroll
        for (int rt = 0; rt < 4; ++rt)
            #pragma unroll
            for (int ct = 0; ct < 4; ++ct)
                acc[rt][ct] = __builtin_amdgcn_mfma_f32_16x16x32_bf16(
                    af[rt], bfr[ct], acc[rt][ct], 0, 0, 0);
    }

    // masked elu + column sums. C layout: row = quad*4+reg, col = r.
    float mrow[4][4];
    #pragma unroll
    for (int rt = 0; rt < 4; ++rt)
        #pragma unroll
        for (int reg = 0; reg < 4; ++reg)
            mrow[rt][reg] = sM[wave * 64 + rt * 16 + quad * 4 + reg];

    #pragma unroll
    for (int ct = 0; ct < 4; ++ct) {
        float bb = sB2[ct * 16 + r];
        float s = 0.0f;
        #pragma unroll
        for (int rt = 0; rt < 4; ++rt)
            #pragma unroll
            for (int reg = 0; reg < 4; ++reg) {
                float v = acc[rt][ct][reg] + bb;
                v = v > 0.0f ? v : (__expf(v) - 1.0f);
                s += mrow[rt][reg] * v;
            }
        s += __shfl_xor(s, 16);
        s += __shfl_xor(s, 32);
        if (quad == 0) sPart[wave][ct * 16 + r] = s;
    }
    __syncthreads();

    // ---- phase 4: combine waves, divide by denom ----
    if (t < 64) {
        float denom = sMsum[0] + sMsum[1] + sMsum[2] + sMsum[3];
        denom = fmaxf(denom, 1.0f);
        float ssum = sPart[0][t] + sPart[1][t] + sPart[2][t] + sPart[3][t];
        hid_mean[p * HN + t] = ssum / denom;
    }
}

// ---------------------------------------------------------------------------
// Stage 2: per person: out = elu(hid_mean@w3+b3)@w4+b4; split mu/logvar;
// ability = mu + eps*exp(0.5*logvar); abilitysum[p] = sum_a ability.
// One block = one person, 64 threads. All f32.
// ---------------------------------------------------------------------------
__global__ __launch_bounds__(64) void k_stage2(
    const float* __restrict__ hid_mean,
    const float* __restrict__ w3,
    const float* __restrict__ b3,
    const float* __restrict__ w4,
    const float* __restrict__ b4,
    const float* __restrict__ eps_ability,
    float* __restrict__ out_amu,
    float* __restrict__ out_alv,
    float* __restrict__ abilitysum)
{
    const int p = blockIdx.x;
    const int k = threadIdx.x;
    __shared__ float shm[64];
    __shared__ float st[64];
    __shared__ float sout[64];

    shm[k] = hid_mean[p * HN + k];
    __syncthreads();

    float acc = b3[k];
    #pragma unroll 8
    for (int j = 0; j < 64; ++j) acc = fmaf(shm[j], w3[j * 64 + k], acc);
    st[k] = eluf(acc);
    __syncthreads();

    float o = b4[k];
    #pragma unroll 8
    for (int j = 0; j < 64; ++j) o = fmaf(st[j], w4[j * 64 + k], o);
    sout[k] = o;
    if (k < 32) {
        out_amu[p * AN + k] = o;
    } else {
        out_alv[p * AN + (k - 32)] = o;
    }
    __syncthreads();

    if (k < 32) {
        float ab = sout[k] + eps_ability[p * AN + k] * __expf(0.5f * sout[k + 32]);
        #pragma unroll
        for (int off = 16; off; off >>= 1) ab += __shfl_xor(ab, off);   // stays within lanes 0..31
        if (k == 0) abilitysum[p] = ab;
    }
}

// ---------------------------------------------------------------------------
// Items: item_mu/item_logvar output gather (tiny)
// ---------------------------------------------------------------------------
__global__ void k_items(
    const int* __restrict__ item_index,
    const float* __restrict__ mu_table,
    const float* __restrict__ logvar_table,
    float* __restrict__ out_imu,
    float* __restrict__ out_ilv)
{
    int i = threadIdx.x;  // 256 threads, 1 block
    int idx = item_index[i];
    out_imu[i] = mu_table[idx];
    out_ilv[i] = logvar_table[idx];
}

// ---------------------------------------------------------------------------
// Response: response_mu[p,i] = sigmoid(abilitysum[p] + item_feat[i])
// item_feat computed per-block in LDS (cheap); 4 items per thread -> 16B f32 stores.
// Fully overwrites the response region (which stage1 may have used as scratch).
// ---------------------------------------------------------------------------
__global__ __launch_bounds__(256) void k_resp(
    const float* __restrict__ abilitysum,
    const int* __restrict__ item_index,
    const float* __restrict__ eps_item,
    const float* __restrict__ mu_table,
    const float* __restrict__ logvar_table,
    float* __restrict__ out_resp)
{
    __shared__ float sIF[256];
    const int t = threadIdx.x;

    // phase A: item_feat[i] = mu_table[idx] + eps_item[i]*exp(0.5*logvar_table[idx])
    {
        int idx = item_index[t];
        sIF[t] = mu_table[idx] + eps_item[t] * __expf(0.5f * logvar_table[idx]);
    }
    __syncthreads();

    // phase B: 4 persons per block, 64 threads per person, 4 items per thread
    int g = blockIdx.x * 256 + t;
    int p = g >> 6;
    int i0 = (g & 63) * 4;
    float a = abilitysum[p];
    f32x4 pk;
    #pragma unroll
    for (int u = 0; u < 4; ++u) {
        float logit = a + sIF[i0 + u];
        pk[u] = 1.0f / (1.0f + __expf(-logit));
    }
    *(f32x4*)&out_resp[p * IN + i0] = pk;
}

extern "C" void kernel_launch(void* const* d_in, const int* in_sizes, int n_in,
                              void* d_out, int out_size, void* d_ws, size_t ws_size,
                              hipStream_t stream)
{
    const float* response     = (const float*)d_in[0];
    const int*   mask         = (const int*)d_in[1];
    const int*   item_index   = (const int*)d_in[2];
    const float* eps_ability  = (const float*)d_in[3];
    const float* eps_item     = (const float*)d_in[4];
    const float* w1           = (const float*)d_in[5];
    const float* b1           = (const float*)d_in[6];
    const float* w2           = (const float*)d_in[7];
    const float* b2           = (const float*)d_in[8];
    const float* w3           = (const float*)d_in[9];
    const float* b3           = (const float*)d_in[10];
    const float* w4           = (const float*)d_in[11];
    const float* b4           = (const float*)d_in[12];
    const float* mu_table     = (const float*)d_in[13];
    const float* logvar_table = (const float*)d_in[14];

    float* out = (float*)d_out;

    // Scratch plan: abilitysum (16 KB) in d_ws; hid_mean (1 MB f32) in d_ws if
    // it fits, else overlaid on the response_mu output region (4 MB f32,
    // fully overwritten by k_resp afterwards). ws_size is constant across
    // calls, so this choice is deterministic (graph-capture safe).
    float* abilitysum = (float*)d_ws;
    float* hid_mean;
    if (ws_size >= (size_t)(PN + PN * HN) * sizeof(float))
        hid_mean = (float*)d_ws + PN;
    else
        hid_mean = out + OFF_RESP;

    k_stage1<<<PN, 256, 0, stream>>>(response, mask, w1, b1, w2, b2, hid_mean);
    k_items<<<1, 256, 0, stream>>>(item_index, mu_table, logvar_table,
                                   out + OFF_IMU, out + OFF_ILV);
    k_stage2<<<PN, 64, 0, stream>>>(hid_mean, w3, b3, w4, b4, eps_ability,
                                    out + OFF_AMU, out + OFF_ALV, abilitysum);
    k_resp<<<PN / 4, 256, 0, stream>>>(abilitysum, item_index, eps_item,
                                       mu_table, logvar_table, out + OFF_RESP);
}

// Round 5
// 134.589 us; speedup vs baseline: 1.0285x; 1.0285x over previous
//
#include <hip/hip_runtime.h>
#include <hip/hip_bf16.h>

// Problem constants
#define PN 4096
#define IN 256
#define HN 64
#define AN 32

// Output layout (FLOAT32 elements), reference return order:
// response_mu (P*I), ability_mu (P*A), ability_logvar (P*A), item_mu (I), item_logvar (I)
#define OFF_RESP 0
#define OFF_AMU  (PN * IN)
#define OFF_ALV  (OFF_AMU + PN * AN)
#define OFF_IMU  (OFF_ALV + PN * AN)
#define OFF_ILV  (OFF_IMU + IN)

typedef short  s16x8  __attribute__((ext_vector_type(8)));   // 8 bf16 bit-patterns
typedef float  f32x4  __attribute__((ext_vector_type(4)));

// round-to-nearest-even f32 -> bf16 bits (scalar fallback path)
__device__ __forceinline__ unsigned short f2bf(float f) {
    union { float f; unsigned int u; } v; v.f = f;
    unsigned int u = v.u;
    u += 0x7FFFu + ((u >> 16) & 1u);
    return (unsigned short)(u >> 16);
}

__device__ __forceinline__ float eluf(float x) {
    return x > 0.0f ? x : (__expf(x) - 1.0f);
}

// pack two f32 -> one dword of two bf16 (HW v_cvt_pk_bf16_f32 on gfx950)
__device__ __forceinline__ unsigned int pack_bf16(float a, float b) {
    union { __hip_bfloat162 h; unsigned int u; } cv;
    cv.h = __float22bfloat162_rn(make_float2(a, b));
    return cv.u;
}

// ---------------------------------------------------------------------------
// Stage 1: per person p (one block, 256 threads, 4 waves):
//   hid_mean[p] = sum_{i active} elu( elu(x_i*w1+b1) @ w2 + b2 ) / max(cnt,1)
// Mask compaction: only active items get h1 rows; MFMA row-tiles beyond the
// active count are skipped entirely. hid_mean stored as bf16.
// ---------------------------------------------------------------------------
__global__ __launch_bounds__(256, 3) void k_stage1(
    const float* __restrict__ response,
    const int* __restrict__ mask,
    const float* __restrict__ w1,
    const float* __restrict__ b1,
    const float* __restrict__ w2,
    const float* __restrict__ b2,
    unsigned short* __restrict__ hidm)   // bf16 bits, [PN][HN]
{
    __shared__ __align__(16) unsigned short sH1[256][72];
    __shared__ __align__(16) unsigned short sW2T[64][72];   // sW2T[n][k] = bf16(w2[k][n])
    __shared__ float sW1[64], sB1[64], sB2[64];
    __shared__ float sM[256];      // 1.0 for compacted-active row, 0.0 for pad
    __shared__ float sX[256];      // compacted x values
    __shared__ int   sWcnt[4];
    __shared__ float sPart[4][64];

    const int t = threadIdx.x;
    const int p = blockIdx.x;
    const int wave = t >> 6;
    const int lane = t & 63;
    const int quad = lane >> 4;
    const int r    = lane & 15;

    // ---- phase 1: stage weights; ballot-compact the active items ----
    if (t < 64) {
        sW1[t] = w1[t];
        sB1[t] = b1[t];
        sB2[t] = b2[t];
    }
    for (int idx = t; idx < 4096; idx += 256)
        sW2T[idx & 63][idx >> 6] = f2bf(w2[idx]);

    float x = response[p * IN + t];
    int   m = mask[p * IN + t];
    unsigned long long act = __ballot(m != 0);
    int rw = __popcll(act & ((1ULL << lane) - 1ULL));
    if (lane == 0) sWcnt[wave] = __popcll(act);
    __syncthreads();

    const int c0 = sWcnt[0], c1 = sWcnt[1], c2 = sWcnt[2], c3 = sWcnt[3];
    const int cnt = c0 + c1 + c2 + c3;
    int base = (wave > 0 ? c0 : 0) + (wave > 1 ? c1 : 0) + (wave > 2 ? c2 : 0);
    if (m) sX[base + rw] = x;
    __syncthreads();

    const int span  = (cnt + 63) & ~63;   // rows padded to wave granularity
    const int tiles = span >> 6;          // active 64-row MFMA chunks (0..4)

    // ---- phase 2: h1 rows for compacted items; zero pad rows ----
    if (t < cnt) {
        float xv = sX[t];
        #pragma unroll
        for (int j0 = 0; j0 < 64; j0 += 8) {
            uint4 pk;
            float a0, a1;
            a0 = eluf(fmaf(xv, sW1[j0+0], sB1[j0+0]));
            a1 = eluf(fmaf(xv, sW1[j0+1], sB1[j0+1]));
            pk.x = pack_bf16(a0, a1);
            a0 = eluf(fmaf(xv, sW1[j0+2], sB1[j0+2]));
            a1 = eluf(fmaf(xv, sW1[j0+3], sB1[j0+3]));
            pk.y = pack_bf16(a0, a1);
            a0 = eluf(fmaf(xv, sW1[j0+4], sB1[j0+4]));
            a1 = eluf(fmaf(xv, sW1[j0+5], sB1[j0+5]));
            pk.z = pack_bf16(a0, a1);
            a0 = eluf(fmaf(xv, sW1[j0+6], sB1[j0+6]));
            a1 = eluf(fmaf(xv, sW1[j0+7], sB1[j0+7]));
            pk.w = pack_bf16(a0, a1);
            *(uint4*)&sH1[t][j0] = pk;
        }
    } else if (t < span) {
        uint4 z = make_uint4(0u, 0u, 0u, 0u);
        #pragma unroll
        for (int j0 = 0; j0 < 64; j0 += 8)
            *(uint4*)&sH1[t][j0] = z;
    }
    sM[t] = (t < cnt) ? 1.0f : 0.0f;
    __syncthreads();

    // ---- phase 3: MFMA span x 64 @ 64 x 64 ; wave w owns rows [64w,64w+64) ----
    if (wave < tiles) {
        f32x4 acc[4][4];
        #pragma unroll
        for (int rt = 0; rt < 4; ++rt)
            #pragma unroll
            for (int ct = 0; ct < 4; ++ct)
                acc[rt][ct] = (f32x4){0.f, 0.f, 0.f, 0.f};

        #pragma unroll
        for (int kk = 0; kk < 64; kk += 32) {
            s16x8 af[4], bfr[4];
            #pragma unroll
            for (int rt = 0; rt < 4; ++rt)
                af[rt] = *(const s16x8*)&sH1[wave * 64 + rt * 16 + r][kk + quad * 8];
            #pragma unroll
            for (int ct = 0; ct < 4; ++ct)
                bfr[ct] = *(const s16x8*)&sW2T[ct * 16 + r][kk + quad * 8];
            #pragma unroll
            for (int rt = 0; rt < 4; ++rt)
                #pragma unroll
                for (int ct = 0; ct < 4; ++ct)
                    acc[rt][ct] = __builtin_amdgcn_mfma_f32_16x16x32_bf16(
                        af[rt], bfr[ct], acc[rt][ct], 0, 0, 0);
        }

        // epilogue: +b2, elu, exclude pad rows, column sums
        float mrow[4][4];
        #pragma unroll
        for (int rt = 0; rt < 4; ++rt)
            #pragma unroll
            for (int reg = 0; reg < 4; ++reg)
                mrow[rt][reg] = sM[wave * 64 + rt * 16 + quad * 4 + reg];

        #pragma unroll
        for (int ct = 0; ct < 4; ++ct) {
            float bb = sB2[ct * 16 + r];
            float s = 0.0f;
            #pragma unroll
            for (int rt = 0; rt < 4; ++rt)
                #pragma unroll
                for (int reg = 0; reg < 4; ++reg) {
                    float v = acc[rt][ct][reg] + bb;
                    v = v > 0.0f ? v : (__expf(v) - 1.0f);   // finite for pad rows (zero A row)
                    s += mrow[rt][reg] * v;
                }
            s += __shfl_xor(s, 16);
            s += __shfl_xor(s, 32);
            if (quad == 0) sPart[wave][ct * 16 + r] = s;
        }
    } else {
        if (quad == 0) {
            #pragma unroll
            for (int ct = 0; ct < 4; ++ct) sPart[wave][ct * 16 + r] = 0.0f;
        }
    }
    __syncthreads();

    // ---- phase 4: combine waves, divide, store bf16 ----
    if (t < 64) {
        float denom = fmaxf((float)cnt, 1.0f);
        float ssum = sPart[0][t] + sPart[1][t] + sPart[2][t] + sPart[3][t];
        hidm[p * HN + t] = f2bf(ssum / denom);
    }
}

// ---------------------------------------------------------------------------
// Fused tail: 64 persons per block, 64 blocks, 256 threads.
//   C1 = hid_mean @ w3 + b3 ; T = elu(C1) ; C2 = T @ w4 + b4
//   amu/alv = C2 split ; abilitysum = sum(amu + eps*exp(0.5*alv))
//   item_feat from tables ; response_mu = sigmoid(abilitysum + item_feat)
// Wave w computes col-tile w (16 cols) of both 64x64 MFMAs.
// ---------------------------------------------------------------------------
__global__ __launch_bounds__(256, 1) void k_tail(
    const unsigned short* __restrict__ hidm,
    const float* __restrict__ w3,
    const float* __restrict__ b3,
    const float* __restrict__ w4,
    const float* __restrict__ b4,
    const float* __restrict__ eps_ability,
    const int* __restrict__ item_index,
    const float* __restrict__ eps_item,
    const float* __restrict__ mu_table,
    const float* __restrict__ logvar_table,
    float* __restrict__ out_amu,
    float* __restrict__ out_alv,
    float* __restrict__ out_imu,
    float* __restrict__ out_ilv,
    float* __restrict__ out_resp)
{
    __shared__ __align__(16) unsigned short sHM[64][72];
    __shared__ __align__(16) unsigned short sW3T[64][72];
    __shared__ __align__(16) unsigned short sW4T[64][72];
    __shared__ __align__(16) unsigned short sT[64][72];
    __shared__ float sOut[64][68];
    __shared__ float sB3[64], sB4[64];
    __shared__ float sAS[64];
    __shared__ float sIF[256];

    const int t = threadIdx.x;
    const int p0 = blockIdx.x * 64;
    const int wave = t >> 6;
    const int lane = t & 63;
    const int quad = lane >> 4;
    const int r    = lane & 15;

    // ---- stage: hid_mean rows (bf16, direct copy), w3/w4 transposed bf16 ----
    {
        const uint4* src = (const uint4*)(hidm + p0 * HN);
        #pragma unroll
        for (int k = 0; k < 2; ++k) {
            int vi = t + 256 * k;            // 512 uint4 = 64 rows x 64 bf16
            uint4 v = src[vi];
            int fu = vi * 8;
            *(uint4*)&sHM[fu >> 6][fu & 63] = v;
        }
    }
    for (int idx = t; idx < 4096; idx += 256) {
        sW3T[idx & 63][idx >> 6] = f2bf(w3[idx]);
        sW4T[idx & 63][idx >> 6] = f2bf(w4[idx]);
    }
    if (t < 64) { sB3[t] = b3[t]; sB4[t] = b4[t]; }
    {
        int idx = item_index[t];
        float mu = mu_table[idx];
        float lv = logvar_table[idx];
        sIF[t] = mu + eps_item[t] * __expf(0.5f * lv);
        if (blockIdx.x == 0) { out_imu[t] = mu; out_ilv[t] = lv; }
    }
    __syncthreads();

    // ---- MFMA 1: C1 = sHM @ w3 ; cols [16*wave, 16*wave+16) ----
    f32x4 acc[4];
    #pragma unroll
    for (int rt = 0; rt < 4; ++rt) acc[rt] = (f32x4){0.f, 0.f, 0.f, 0.f};
    #pragma unroll
    for (int kk = 0; kk < 64; kk += 32) {
        s16x8 bfr = *(const s16x8*)&sW3T[wave * 16 + r][kk + quad * 8];
        #pragma unroll
        for (int rt = 0; rt < 4; ++rt) {
            s16x8 af = *(const s16x8*)&sHM[rt * 16 + r][kk + quad * 8];
            acc[rt] = __builtin_amdgcn_mfma_f32_16x16x32_bf16(af, bfr, acc[rt], 0, 0, 0);
        }
    }
    {
        int col = wave * 16 + r;
        float bb = sB3[col];
        #pragma unroll
        for (int rt = 0; rt < 4; ++rt)
            #pragma unroll
            for (int reg = 0; reg < 4; ++reg) {
                float v = acc[rt][reg] + bb;
                v = v > 0.0f ? v : (__expf(v) - 1.0f);
                sT[rt * 16 + quad * 4 + reg][col] = f2bf(v);
            }
    }
    __syncthreads();

    // ---- MFMA 2: C2 = sT @ w4 ----
    f32x4 acc2[4];
    #pragma unroll
    for (int rt = 0; rt < 4; ++rt) acc2[rt] = (f32x4){0.f, 0.f, 0.f, 0.f};
    #pragma unroll
    for (int kk = 0; kk < 64; kk += 32) {
        s16x8 bfr = *(const s16x8*)&sW4T[wave * 16 + r][kk + quad * 8];
        #pragma unroll
        for (int rt = 0; rt < 4; ++rt) {
            s16x8 af = *(const s16x8*)&sT[rt * 16 + r][kk + quad * 8];
            acc2[rt] = __builtin_amdgcn_mfma_f32_16x16x32_bf16(af, bfr, acc2[rt], 0, 0, 0);
        }
    }
    {
        int col = wave * 16 + r;
        float bb = sB4[col];
        #pragma unroll
        for (int rt = 0; rt < 4; ++rt)
            #pragma unroll
            for (int reg = 0; reg < 4; ++reg)
                sOut[rt * 16 + quad * 4 + reg][col] = acc2[rt][reg] + bb;
    }
    __syncthreads();

    // ---- amu/alv outputs + abilitysum ----
    #pragma unroll
    for (int k = 0; k < 8; ++k) {
        int flat = t + 256 * k;          // 2048 = 64 persons x 32
        int pl = flat >> 5, a = flat & 31;
        float mu = sOut[pl][a];
        float lv = sOut[pl][a + 32];
        out_amu[(p0 + pl) * AN + a] = mu;
        out_alv[(p0 + pl) * AN + a] = lv;
        float partial = mu + eps_ability[(p0 + pl) * AN + a] * __expf(0.5f * lv);
        #pragma unroll
        for (int off = 16; off; off >>= 1) partial += __shfl_xor(partial, off);
        if (a == 0) sAS[pl] = partial;
    }
    __syncthreads();

    // ---- response: sigmoid(abilitysum[p] + item_feat[i]) ----
    #pragma unroll
    for (int k = 0; k < 16; ++k) {
        int vi = t + 256 * k;            // 4096 f32x4 = 64 persons x 256 items
        int pl = vi >> 6, i0 = (vi & 63) * 4;
        float a = sAS[pl];
        f32x4 pk;
        #pragma unroll
        for (int u = 0; u < 4; ++u)
            pk[u] = 1.0f / (1.0f + __expf(-(a + sIF[i0 + u])));
        *(f32x4*)&out_resp[(p0 + pl) * IN + i0] = pk;
    }
}

extern "C" void kernel_launch(void* const* d_in, const int* in_sizes, int n_in,
                              void* d_out, int out_size, void* d_ws, size_t ws_size,
                              hipStream_t stream)
{
    const float* response     = (const float*)d_in[0];
    const int*   mask         = (const int*)d_in[1];
    const int*   item_index   = (const int*)d_in[2];
    const float* eps_ability  = (const float*)d_in[3];
    const float* eps_item     = (const float*)d_in[4];
    const float* w1           = (const float*)d_in[5];
    const float* b1           = (const float*)d_in[6];
    const float* w2           = (const float*)d_in[7];
    const float* b2           = (const float*)d_in[8];
    const float* w3           = (const float*)d_in[9];
    const float* b3           = (const float*)d_in[10];
    const float* w4           = (const float*)d_in[11];
    const float* b4           = (const float*)d_in[12];
    const float* mu_table     = (const float*)d_in[13];
    const float* logvar_table = (const float*)d_in[14];

    float* out = (float*)d_out;

    // hid_mean bf16 (512 KB): d_ws if it fits, else overlay on out_amu region.
    // Overlay is safe: k_tail block b reads exactly the hidm words of its own
    // persons (dwords [2048b,2048b+2048)) during staging, then writes out_amu
    // over the same range only after later barriers — no cross-block overlap.
    unsigned short* hidm;
    if (ws_size >= (size_t)(PN * HN) * sizeof(unsigned short))
        hidm = (unsigned short*)d_ws;
    else
        hidm = (unsigned short*)(out + OFF_AMU);

    k_stage1<<<PN, 256, 0, stream>>>(response, mask, w1, b1, w2, b2, hidm);
    k_tail<<<PN / 64, 256, 0, stream>>>(hidm, w3, b3, w4, b4, eps_ability,
                                        item_index, eps_item, mu_table, logvar_table,
                                        out + OFF_AMU, out + OFF_ALV,
                                        out + OFF_IMU, out + OFF_ILV,
                                        out + OFF_RESP);
}

// Round 6
// 131.404 us; speedup vs baseline: 1.0535x; 1.0242x over previous
//
#include <hip/hip_runtime.h>
#include <hip/hip_bf16.h>

// Problem constants
#define PN 4096
#define IN 256
#define HN 64
#define AN 32

// Output layout (FLOAT32 elements), reference return order:
// response_mu (P*I), ability_mu (P*A), ability_logvar (P*A), item_mu (I), item_logvar (I)
#define OFF_RESP 0
#define OFF_AMU  (PN * IN)
#define OFF_ALV  (OFF_AMU + PN * AN)
#define OFF_IMU  (OFF_ALV + PN * AN)
#define OFF_ILV  (OFF_IMU + IN)

// Lookup table: f(x) = elu( elu(x*w1+b1) @ w2 + b2 ) sampled on 192 grid points.
#define TROWS   192
#define TSTRIDE 68            // dwords per row (68%32=4 bank rotation; 272B = 16B-aligned)

typedef short  s16x8  __attribute__((ext_vector_type(8)));
typedef float  f32x4  __attribute__((ext_vector_type(4)));

__device__ __forceinline__ unsigned short f2bf(float f) {
    union { float f; unsigned int u; } v; v.f = f;
    unsigned int u = v.u;
    u += 0x7FFFu + ((u >> 16) & 1u);
    return (unsigned short)(u >> 16);
}

__device__ __forceinline__ float eluf(float x) {
    return x > 0.0f ? x : (__expf(x) - 1.0f);
}

__device__ __forceinline__ unsigned int pack_bf16(float a, float b) {
    union { __hip_bfloat162 h; unsigned int u; } cv;
    cv.h = __float22bfloat162_rn(make_float2(a, b));
    return cv.u;
}

// ---------------------------------------------------------------------------
// Stage 1 (lookup-table): grid 256 blocks x 256 threads, 16 persons/block.
// Prelude: build T[g][j] = f(g/191)[j] in LDS via one 192x64 @ 64x64 MFMA.
// Per person: hid_mean[j] = (1/cnt) * sum_i m_i * lerp(T, x_i)[j].
// ---------------------------------------------------------------------------
__global__ __launch_bounds__(256, 1) void k_stage1(
    const float* __restrict__ response,
    const int* __restrict__ mask,
    const float* __restrict__ w1,
    const float* __restrict__ b1,
    const float* __restrict__ w2,
    const float* __restrict__ b2,
    unsigned short* __restrict__ hidm)   // bf16 bits, [PN][HN]
{
    // Region A: first holds sH1 (192x72 bf16) + sW2T (64x72 bf16), then is
    // overwritten (after a barrier) by the f32 table sT[192][TSTRIDE].
    __shared__ __align__(16) float sT[TROWS * TSTRIDE];          // 52,224 B
    __shared__ float sW1[64], sB1[64], sB2[64];
    __shared__ __align__(16) float4 sA[256];                     // {a0, a1, rowbyteofs, -}
    __shared__ float sPart[4][64];
    __shared__ int   sCnt[4];

    unsigned short* sH1  = (unsigned short*)sT;                  // [192][72]
    unsigned short* sW2T = (unsigned short*)sT + 192 * 72;       // [64][72]

    const int t    = threadIdx.x;
    const int p0   = blockIdx.x * 16;
    const int wave = t >> 6;
    const int lane = t & 63;
    const int quad = lane >> 4;
    const int r    = lane & 15;

    // ---- issue all 16 persons' x/mask loads up front (latency hidden behind table build)
    float xv[16]; int mv[16];
    #pragma unroll
    for (int pp = 0; pp < 16; ++pp) {
        xv[pp] = response[(p0 + pp) * IN + t];
        mv[pp] = mask[(p0 + pp) * IN + t];
    }

    // ---- stage weights ----
    if (t < 64) { sW1[t] = w1[t]; sB1[t] = b1[t]; sB2[t] = b2[t]; }
    for (int idx = t; idx < 4096; idx += 256)
        sW2T[(idx & 63) * 72 + (idx >> 6)] = f2bf(w2[idx]);
    __syncthreads();

    // ---- grid rows: h1(g) = elu(x_g * w1 + b1), x_g = g/191 ----
    if (t < TROWS) {
        float xg = (float)t * (1.0f / 191.0f);
        #pragma unroll
        for (int j0 = 0; j0 < 64; j0 += 8) {
            uint4 pk;
            pk.x = pack_bf16(eluf(fmaf(xg, sW1[j0+0], sB1[j0+0])),
                             eluf(fmaf(xg, sW1[j0+1], sB1[j0+1])));
            pk.y = pack_bf16(eluf(fmaf(xg, sW1[j0+2], sB1[j0+2])),
                             eluf(fmaf(xg, sW1[j0+3], sB1[j0+3])));
            pk.z = pack_bf16(eluf(fmaf(xg, sW1[j0+4], sB1[j0+4])),
                             eluf(fmaf(xg, sW1[j0+5], sB1[j0+5])));
            pk.w = pack_bf16(eluf(fmaf(xg, sW1[j0+6], sB1[j0+6])),
                             eluf(fmaf(xg, sW1[j0+7], sB1[j0+7])));
            *(uint4*)&sH1[t * 72 + j0] = pk;
        }
    }
    __syncthreads();

    // ---- MFMA: 192x64 @ 64x64 ; waves 0..2 own 64-row tiles ----
    f32x4 acc[4][4];
    if (wave < 3) {
        #pragma unroll
        for (int rt = 0; rt < 4; ++rt)
            #pragma unroll
            for (int ct = 0; ct < 4; ++ct)
                acc[rt][ct] = (f32x4){0.f, 0.f, 0.f, 0.f};
        #pragma unroll
        for (int kk = 0; kk < 64; kk += 32) {
            s16x8 af[4], bfr[4];
            #pragma unroll
            for (int rt = 0; rt < 4; ++rt)
                af[rt] = *(const s16x8*)&sH1[(wave * 64 + rt * 16 + r) * 72 + kk + quad * 8];
            #pragma unroll
            for (int ct = 0; ct < 4; ++ct)
                bfr[ct] = *(const s16x8*)&sW2T[(ct * 16 + r) * 72 + kk + quad * 8];
            #pragma unroll
            for (int rt = 0; rt < 4; ++rt)
                #pragma unroll
                for (int ct = 0; ct < 4; ++ct)
                    acc[rt][ct] = __builtin_amdgcn_mfma_f32_16x16x32_bf16(
                        af[rt], bfr[ct], acc[rt][ct], 0, 0, 0);
        }
    }
    __syncthreads();   // all waves done READING region A

    // ---- epilogue: T = elu(acc + b2) as f32, overwriting region A ----
    if (wave < 3) {
        #pragma unroll
        for (int ct = 0; ct < 4; ++ct) {
            int col = ct * 16 + r;
            float bb = sB2[col];
            #pragma unroll
            for (int rt = 0; rt < 4; ++rt)
                #pragma unroll
                for (int reg = 0; reg < 4; ++reg) {
                    int row = wave * 64 + rt * 16 + quad * 4 + reg;
                    sT[row * TSTRIDE + col] = eluf(acc[rt][ct][reg] + bb);
                }
        }
    }
    __syncthreads();

    // ---- 16 persons: masked lerp-gather-sum ----
    #pragma unroll
    for (int pp = 0; pp < 16; ++pp) {
        float x = xv[pp];
        float m = (mv[pp] != 0) ? 1.0f : 0.0f;
        float kf = x * 191.0f;
        int k = (int)kf;
        k = (k < 0) ? 0 : ((k > 190) ? 190 : k);
        float w  = kf - (float)k;
        float a1 = w * m;
        float a0 = m - a1;
        sA[t] = make_float4(a0, a1, __int_as_float(k * (TSTRIDE * 4)), 0.0f);
        unsigned long long act = __ballot(mv[pp] != 0);
        if (lane == 0) sCnt[wave] = __popcll(act);
        __syncthreads();

        float cnt = (float)(sCnt[0] + sCnt[1] + sCnt[2] + sCnt[3]);
        float acc1 = 0.0f;
        #pragma unroll
        for (int it = 0; it < 64; ++it) {
            float4 A = sA[wave * 64 + it];                 // b128 broadcast
            const float* rowp = (const float*)((const char*)sT + __float_as_int(A.z)) + lane;
            float T0 = rowp[0];
            float T1 = rowp[TSTRIDE];
            acc1 = fmaf(A.x, T0, acc1);
            acc1 = fmaf(A.y, T1, acc1);
        }
        sPart[wave][lane] = acc1;
        __syncthreads();
        if (t < 64) {
            float s = sPart[0][t] + sPart[1][t] + sPart[2][t] + sPart[3][t];
            hidm[(p0 + pp) * HN + t] = f2bf(s / fmaxf(cnt, 1.0f));
        }
    }
}

// ---------------------------------------------------------------------------
// Fused tail: 64 persons per block, 64 blocks, 256 threads. (unchanged, r5)
// ---------------------------------------------------------------------------
__global__ __launch_bounds__(256, 1) void k_tail(
    const unsigned short* __restrict__ hidm,
    const float* __restrict__ w3,
    const float* __restrict__ b3,
    const float* __restrict__ w4,
    const float* __restrict__ b4,
    const float* __restrict__ eps_ability,
    const int* __restrict__ item_index,
    const float* __restrict__ eps_item,
    const float* __restrict__ mu_table,
    const float* __restrict__ logvar_table,
    float* __restrict__ out_amu,
    float* __restrict__ out_alv,
    float* __restrict__ out_imu,
    float* __restrict__ out_ilv,
    float* __restrict__ out_resp)
{
    __shared__ __align__(16) unsigned short sHM[64][72];
    __shared__ __align__(16) unsigned short sW3T[64][72];
    __shared__ __align__(16) unsigned short sW4T[64][72];
    __shared__ __align__(16) unsigned short sT[64][72];
    __shared__ float sOut[64][68];
    __shared__ float sB3[64], sB4[64];
    __shared__ float sAS[64];
    __shared__ float sIF[256];

    const int t = threadIdx.x;
    const int p0 = blockIdx.x * 64;
    const int wave = t >> 6;
    const int lane = t & 63;
    const int quad = lane >> 4;
    const int r    = lane & 15;

    {
        const uint4* src = (const uint4*)(hidm + p0 * HN);
        #pragma unroll
        for (int k = 0; k < 2; ++k) {
            int vi = t + 256 * k;
            uint4 v = src[vi];
            int fu = vi * 8;
            *(uint4*)&sHM[fu >> 6][fu & 63] = v;
        }
    }
    for (int idx = t; idx < 4096; idx += 256) {
        sW3T[idx & 63][idx >> 6] = f2bf(w3[idx]);
        sW4T[idx & 63][idx >> 6] = f2bf(w4[idx]);
    }
    if (t < 64) { sB3[t] = b3[t]; sB4[t] = b4[t]; }
    {
        int idx = item_index[t];
        float mu = mu_table[idx];
        float lv = logvar_table[idx];
        sIF[t] = mu + eps_item[t] * __expf(0.5f * lv);
        if (blockIdx.x == 0) { out_imu[t] = mu; out_ilv[t] = lv; }
    }
    __syncthreads();

    f32x4 acc[4];
    #pragma unroll
    for (int rt = 0; rt < 4; ++rt) acc[rt] = (f32x4){0.f, 0.f, 0.f, 0.f};
    #pragma unroll
    for (int kk = 0; kk < 64; kk += 32) {
        s16x8 bfr = *(const s16x8*)&sW3T[wave * 16 + r][kk + quad * 8];
        #pragma unroll
        for (int rt = 0; rt < 4; ++rt) {
            s16x8 af = *(const s16x8*)&sHM[rt * 16 + r][kk + quad * 8];
            acc[rt] = __builtin_amdgcn_mfma_f32_16x16x32_bf16(af, bfr, acc[rt], 0, 0, 0);
        }
    }
    {
        int col = wave * 16 + r;
        float bb = sB3[col];
        #pragma unroll
        for (int rt = 0; rt < 4; ++rt)
            #pragma unroll
            for (int reg = 0; reg < 4; ++reg) {
                float v = acc[rt][reg] + bb;
                v = v > 0.0f ? v : (__expf(v) - 1.0f);
                sT[rt * 16 + quad * 4 + reg][col] = f2bf(v);
            }
    }
    __syncthreads();

    f32x4 acc2[4];
    #pragma unroll
    for (int rt = 0; rt < 4; ++rt) acc2[rt] = (f32x4){0.f, 0.f, 0.f, 0.f};
    #pragma unroll
    for (int kk = 0; kk < 64; kk += 32) {
        s16x8 bfr = *(const s16x8*)&sW4T[wave * 16 + r][kk + quad * 8];
        #pragma unroll
        for (int rt = 0; rt < 4; ++rt) {
            s16x8 af = *(const s16x8*)&sT[rt * 16 + r][kk + quad * 8];
            acc2[rt] = __builtin_amdgcn_mfma_f32_16x16x32_bf16(af, bfr, acc2[rt], 0, 0, 0);
        }
    }
    {
        int col = wave * 16 + r;
        float bb = sB4[col];
        #pragma unroll
        for (int rt = 0; rt < 4; ++rt)
            #pragma unroll
            for (int reg = 0; reg < 4; ++reg)
                sOut[rt * 16 + quad * 4 + reg][col] = acc2[rt][reg] + bb;
    }
    __syncthreads();

    #pragma unroll
    for (int k = 0; k < 8; ++k) {
        int flat = t + 256 * k;
        int pl = flat >> 5, a = flat & 31;
        float mu = sOut[pl][a];
        float lv = sOut[pl][a + 32];
        out_amu[(p0 + pl) * AN + a] = mu;
        out_alv[(p0 + pl) * AN + a] = lv;
        float partial = mu + eps_ability[(p0 + pl) * AN + a] * __expf(0.5f * lv);
        #pragma unroll
        for (int off = 16; off; off >>= 1) partial += __shfl_xor(partial, off);
        if (a == 0) sAS[pl] = partial;
    }
    __syncthreads();

    #pragma unroll
    for (int k = 0; k < 16; ++k) {
        int vi = t + 256 * k;
        int pl = vi >> 6, i0 = (vi & 63) * 4;
        float a = sAS[pl];
        f32x4 pk;
        #pragma unroll
        for (int u = 0; u < 4; ++u)
            pk[u] = 1.0f / (1.0f + __expf(-(a + sIF[i0 + u])));
        *(f32x4*)&out_resp[(p0 + pl) * IN + i0] = pk;
    }
}

extern "C" void kernel_launch(void* const* d_in, const int* in_sizes, int n_in,
                              void* d_out, int out_size, void* d_ws, size_t ws_size,
                              hipStream_t stream)
{
    const float* response     = (const float*)d_in[0];
    const int*   mask         = (const int*)d_in[1];
    const int*   item_index   = (const int*)d_in[2];
    const float* eps_ability  = (const float*)d_in[3];
    const float* eps_item     = (const float*)d_in[4];
    const float* w1           = (const float*)d_in[5];
    const float* b1           = (const float*)d_in[6];
    const float* w2           = (const float*)d_in[7];
    const float* b2           = (const float*)d_in[8];
    const float* w3           = (const float*)d_in[9];
    const float* b3           = (const float*)d_in[10];
    const float* w4           = (const float*)d_in[11];
    const float* b4           = (const float*)d_in[12];
    const float* mu_table     = (const float*)d_in[13];
    const float* logvar_table = (const float*)d_in[14];

    float* out = (float*)d_out;

    // hid_mean bf16 (512 KB): d_ws if it fits, else overlay on out_amu region
    // (k_tail block b reads only its own persons' hidm words before writing
    // out_amu over the same range — safe, as in round 5).
    unsigned short* hidm;
    if (ws_size >= (size_t)(PN * HN) * sizeof(unsigned short))
        hidm = (unsigned short*)d_ws;
    else
        hidm = (unsigned short*)(out + OFF_AMU);

    k_stage1<<<PN / 16, 256, 0, stream>>>(response, mask, w1, b1, w2, b2, hidm);
    k_tail<<<PN / 64, 256, 0, stream>>>(hidm, w3, b3, w4, b4, eps_ability,
                                        item_index, eps_item, mu_table, logvar_table,
                                        out + OFF_AMU, out + OFF_ALV,
                                        out + OFF_IMU, out + OFF_ILV,
                                        out + OFF_RESP);
}

// Round 7
// 99.860 us; speedup vs baseline: 1.3862x; 1.3159x over previous
//
#include <hip/hip_runtime.h>
#include <hip/hip_bf16.h>

// Problem constants
#define PN 4096
#define IN 256
#define HN 64
#define AN 32

// Output layout (FLOAT32 elements), reference return order:
// response_mu (P*I), ability_mu (P*A), ability_logvar (P*A), item_mu (I), item_logvar (I)
#define OFF_RESP 0
#define OFF_AMU  (PN * IN)
#define OFF_ALV  (OFF_AMU + PN * AN)
#define OFF_IMU  (OFF_ALV + PN * AN)
#define OFF_ILV  (OFF_IMU + IN)

// f(x) = elu( elu(x*w1+b1) @ w2 + b2 ) sampled on 128 grid points, x ∈ [0,1].
#define TROWS 128

typedef short  s16x8  __attribute__((ext_vector_type(8)));
typedef float  f32x4  __attribute__((ext_vector_type(4)));

__device__ __forceinline__ unsigned short f2bf(float f) {
    union { float f; unsigned int u; } v; v.f = f;
    unsigned int u = v.u;
    u += 0x7FFFu + ((u >> 16) & 1u);
    return (unsigned short)(u >> 16);
}

__device__ __forceinline__ float eluf(float x) {
    return x > 0.0f ? x : (__expf(x) - 1.0f);
}

__device__ __forceinline__ unsigned int pack_bf16(float a, float b) {
    union { __hip_bfloat162 h; unsigned int u; } cv;
    cv.h = __float22bfloat162_rn(make_float2(a, b));
    return cv.u;
}

// ---------------------------------------------------------------------------
// Fully fused kernel: 256 blocks x 256 threads, 16 persons/block.
//  1. build table T[128][64] = f(grid) via MFMA (as r5/r6, verified)
//  2. scatter items into per-person weight rows W[16][128] (LDS f32 atomics)
//  3. hid_mean = (W @ T) / cnt              (MFMA, M=16, K=128)
//  4. t2 = elu(hid @ w3 + b3)               (MFMA, M=16, K=64)
//  5. out = t2 @ w4 + b4                    (MFMA, M=16, K=64)
//  6. amu/alv, abilitysum, item_feat, response sigmoid — all in-block.
// ---------------------------------------------------------------------------
__global__ __launch_bounds__(256, 1) void k_fused(
    const float* __restrict__ response,
    const int* __restrict__ mask,
    const float* __restrict__ w1,
    const float* __restrict__ b1,
    const float* __restrict__ w2,
    const float* __restrict__ b2,
    const float* __restrict__ w3,
    const float* __restrict__ b3,
    const float* __restrict__ w4,
    const float* __restrict__ b4,
    const float* __restrict__ eps_ability,
    const int* __restrict__ item_index,
    const float* __restrict__ eps_item,
    const float* __restrict__ mu_table,
    const float* __restrict__ logvar_table,
    float* __restrict__ out_amu,
    float* __restrict__ out_alv,
    float* __restrict__ out_imu,
    float* __restrict__ out_ilv,
    float* __restrict__ out_resp)
{
    // Region A (27648 B), time-multiplexed with barriers between roles:
    //   role 1: sH1[128][72]us (18432 B) + sW2T[64][72]us (9216 B)
    //   role 2: sTB[64][136]us (17408 B)   (table, B-operand layout)
    //   role 3: sHMB[16][72]us + sT2[16][72]us + sOut[16][68]f32
    __shared__ __align__(16) unsigned char sRegA[27648];
    __shared__ float sW[16 * 132];                     // f32 scatter bins (stride 132)
    __shared__ __align__(16) unsigned short sWB[16 * 136];  // bf16 W, A-operand
    __shared__ __align__(16) unsigned short sW3T[64 * 72];
    __shared__ __align__(16) unsigned short sW4T[64 * 72];
    __shared__ float sW1[64], sB1[64], sB2[64], sB3[64], sB4[64];
    __shared__ float sIF[256];
    __shared__ int   sCnt[16];
    __shared__ float sAS[16];

    unsigned short* sH1  = (unsigned short*)sRegA;              // [128][72]
    unsigned short* sW2T = (unsigned short*)sRegA + 128 * 72;   // [64][72]
    unsigned short* sTB  = (unsigned short*)sRegA;              // [64][136]
    unsigned short* sHMB = (unsigned short*)sRegA;              // [16][72]
    unsigned short* sT2  = (unsigned short*)sRegA + 16 * 72;    // [16][72]
    float*          sOut = (float*)(sRegA + 2 * 16 * 72 * 2);   // [16][68]

    const int t    = threadIdx.x;
    const int p0   = blockIdx.x * 16;
    const int wave = t >> 6;
    const int lane = t & 63;
    const int quad = lane >> 4;
    const int r    = lane & 15;

    // ---- phase 1: upfront person loads + stage everything + zero bins ----
    float xv[16]; int mv[16];
    #pragma unroll
    for (int pp = 0; pp < 16; ++pp) {
        xv[pp] = response[(p0 + pp) * IN + t];
        mv[pp] = mask[(p0 + pp) * IN + t];
    }
    if (t < 64) {
        sW1[t] = w1[t]; sB1[t] = b1[t]; sB2[t] = b2[t];
        sB3[t] = b3[t]; sB4[t] = b4[t];
    }
    // transposed bf16 weight staging (float4 loads, b16 scatter stores)
    for (int base = t * 4; base < 4096; base += 1024) {
        int j = base >> 6, n0 = base & 63;
        float4 v2 = *(const float4*)&w2[base];
        sW2T[(n0 + 0) * 72 + j] = f2bf(v2.x);
        sW2T[(n0 + 1) * 72 + j] = f2bf(v2.y);
        sW2T[(n0 + 2) * 72 + j] = f2bf(v2.z);
        sW2T[(n0 + 3) * 72 + j] = f2bf(v2.w);
        float4 v3 = *(const float4*)&w3[base];
        sW3T[(n0 + 0) * 72 + j] = f2bf(v3.x);
        sW3T[(n0 + 1) * 72 + j] = f2bf(v3.y);
        sW3T[(n0 + 2) * 72 + j] = f2bf(v3.z);
        sW3T[(n0 + 3) * 72 + j] = f2bf(v3.w);
        float4 v4 = *(const float4*)&w4[base];
        sW4T[(n0 + 0) * 72 + j] = f2bf(v4.x);
        sW4T[(n0 + 1) * 72 + j] = f2bf(v4.y);
        sW4T[(n0 + 2) * 72 + j] = f2bf(v4.z);
        sW4T[(n0 + 3) * 72 + j] = f2bf(v4.w);
    }
    {
        int idx = item_index[t];
        float mu = mu_table[idx];
        float lv = logvar_table[idx];
        sIF[t] = mu + eps_item[t] * __expf(0.5f * lv);
        if (blockIdx.x == 0) { out_imu[t] = mu; out_ilv[t] = lv; }
    }
    for (int idx = t; idx < 16 * 132; idx += 256) sW[idx] = 0.0f;
    if (t < 16) sCnt[t] = 0;
    __syncthreads();

    // ---- phase 2: h1 grid rows (bf16) + item scatter into W bins ----
    if (t < TROWS) {
        float xg = (float)t * (1.0f / 127.0f);
        #pragma unroll
        for (int j0 = 0; j0 < 64; j0 += 8) {
            uint4 pk;
            pk.x = pack_bf16(eluf(fmaf(xg, sW1[j0+0], sB1[j0+0])),
                             eluf(fmaf(xg, sW1[j0+1], sB1[j0+1])));
            pk.y = pack_bf16(eluf(fmaf(xg, sW1[j0+2], sB1[j0+2])),
                             eluf(fmaf(xg, sW1[j0+3], sB1[j0+3])));
            pk.z = pack_bf16(eluf(fmaf(xg, sW1[j0+4], sB1[j0+4])),
                             eluf(fmaf(xg, sW1[j0+5], sB1[j0+5])));
            pk.w = pack_bf16(eluf(fmaf(xg, sW1[j0+6], sB1[j0+6])),
                             eluf(fmaf(xg, sW1[j0+7], sB1[j0+7])));
            *(uint4*)&sH1[t * 72 + j0] = pk;
        }
    }
    #pragma unroll
    for (int pp = 0; pp < 16; ++pp) {
        bool on = (mv[pp] != 0);
        unsigned long long act = __ballot(on);
        if (lane == 0) atomicAdd(&sCnt[pp], (int)__popcll(act));
        if (on) {
            float kf = xv[pp] * 127.0f;
            int k = (int)kf;
            k = (k < 0) ? 0 : ((k > 126) ? 126 : k);
            float w = kf - (float)k;
            atomicAdd(&sW[pp * 132 + k],     1.0f - w);
            atomicAdd(&sW[pp * 132 + k + 1], w);
        }
    }
    __syncthreads();

    // ---- phase 3: table MFMA 128x64 @ 64x64 ; wave owns rows [32w,32w+32) ----
    f32x4 accT[2][4];
    #pragma unroll
    for (int rt = 0; rt < 2; ++rt)
        #pragma unroll
        for (int ct = 0; ct < 4; ++ct)
            accT[rt][ct] = (f32x4){0.f, 0.f, 0.f, 0.f};
    #pragma unroll
    for (int kk = 0; kk < 64; kk += 32) {
        s16x8 af[2], bfr[4];
        #pragma unroll
        for (int rt = 0; rt < 2; ++rt)
            af[rt] = *(const s16x8*)&sH1[(wave * 32 + rt * 16 + r) * 72 + kk + quad * 8];
        #pragma unroll
        for (int ct = 0; ct < 4; ++ct)
            bfr[ct] = *(const s16x8*)&sW2T[(ct * 16 + r) * 72 + kk + quad * 8];
        #pragma unroll
        for (int rt = 0; rt < 2; ++rt)
            #pragma unroll
            for (int ct = 0; ct < 4; ++ct)
                accT[rt][ct] = __builtin_amdgcn_mfma_f32_16x16x32_bf16(
                    af[rt], bfr[ct], accT[rt][ct], 0, 0, 0);
    }
    __syncthreads();   // all waves done reading sH1/sW2T

    // ---- phase 4: TB[col][k] = bf16(elu(acc+b2)) ; convert W -> bf16 WB ----
    #pragma unroll
    for (int ct = 0; ct < 4; ++ct) {
        int col = ct * 16 + r;
        float bb = sB2[col];
        #pragma unroll
        for (int rt = 0; rt < 2; ++rt)
            #pragma unroll
            for (int reg = 0; reg < 4; ++reg) {
                int krow = wave * 32 + rt * 16 + quad * 4 + reg;
                sTB[col * 136 + krow] = f2bf(eluf(accT[rt][ct][reg] + bb));
            }
    }
    #pragma unroll
    for (int idx = t; idx < 1024; idx += 256) {       // 16 rows x 64 dword-pairs
        int row = idx >> 6, kp = (idx & 63) * 2;
        ((unsigned int*)sWB)[row * 68 + (idx & 63)] =
            pack_bf16(sW[row * 132 + kp], sW[row * 132 + kp + 1]);
    }
    __syncthreads();

    // ---- phase 5: hid = W(16x128) @ T(128x64) ; wave owns col-tile 16w ----
    f32x4 accH = (f32x4){0.f, 0.f, 0.f, 0.f};
    #pragma unroll
    for (int s = 0; s < 4; ++s) {
        s16x8 af = *(const s16x8*)&sWB[r * 136 + s * 32 + quad * 8];
        s16x8 bfr = *(const s16x8*)&sTB[(wave * 16 + r) * 136 + s * 32 + quad * 8];
        accH = __builtin_amdgcn_mfma_f32_16x16x32_bf16(af, bfr, accH, 0, 0, 0);
    }
    __syncthreads();   // all waves done reading sTB (region A reused below)

    // ---- phase 6: sHMB[person][col] = bf16(hid / max(cnt,1)) ----
    {
        int col = wave * 16 + r;
        #pragma unroll
        for (int reg = 0; reg < 4; ++reg) {
            int person = quad * 4 + reg;
            float c = fmaxf((float)sCnt[person], 1.0f);
            sHMB[person * 72 + col] = f2bf(accH[reg] / c);
        }
    }
    __syncthreads();

    // ---- phase 7: t2 = elu(hid @ w3 + b3) ----
    f32x4 accA = (f32x4){0.f, 0.f, 0.f, 0.f};
    #pragma unroll
    for (int kk = 0; kk < 64; kk += 32) {
        s16x8 af = *(const s16x8*)&sHMB[r * 72 + kk + quad * 8];
        s16x8 bfr = *(const s16x8*)&sW3T[(wave * 16 + r) * 72 + kk + quad * 8];
        accA = __builtin_amdgcn_mfma_f32_16x16x32_bf16(af, bfr, accA, 0, 0, 0);
    }
    {
        int col = wave * 16 + r;
        float bb = sB3[col];
        #pragma unroll
        for (int reg = 0; reg < 4; ++reg)
            sT2[(quad * 4 + reg) * 72 + col] = f2bf(eluf(accA[reg] + bb));
    }
    __syncthreads();

    // ---- phase 8: out = t2 @ w4 + b4 -> sOut f32 ----
    f32x4 accB = (f32x4){0.f, 0.f, 0.f, 0.f};
    #pragma unroll
    for (int kk = 0; kk < 64; kk += 32) {
        s16x8 af = *(const s16x8*)&sT2[r * 72 + kk + quad * 8];
        s16x8 bfr = *(const s16x8*)&sW4T[(wave * 16 + r) * 72 + kk + quad * 8];
        accB = __builtin_amdgcn_mfma_f32_16x16x32_bf16(af, bfr, accB, 0, 0, 0);
    }
    {
        int col = wave * 16 + r;
        float bb = sB4[col];
        #pragma unroll
        for (int reg = 0; reg < 4; ++reg)
            sOut[(quad * 4 + reg) * 68 + col] = accB[reg] + bb;
    }
    __syncthreads();

    // ---- phase 9: amu/alv outputs + abilitysum ----
    #pragma unroll
    for (int k2 = 0; k2 < 2; ++k2) {
        int flat = t + 256 * k2;             // 512 = 16 persons x 32
        int pl = flat >> 5, a = flat & 31;
        float mu = sOut[pl * 68 + a];
        float lv = sOut[pl * 68 + a + 32];
        out_amu[(p0 + pl) * AN + a] = mu;
        out_alv[(p0 + pl) * AN + a] = lv;
        float partial = mu + eps_ability[(p0 + pl) * AN + a] * __expf(0.5f * lv);
        #pragma unroll
        for (int off = 16; off; off >>= 1) partial += __shfl_xor(partial, off);
        if (a == 0) sAS[pl] = partial;
    }
    __syncthreads();

    // ---- phase 10: response sigmoid, 16B stores ----
    #pragma unroll
    for (int k3 = 0; k3 < 4; ++k3) {
        int vi = t + 256 * k3;               // 1024 f32x4 = 16 persons x 256 items
        int pl = vi >> 6, i0 = (vi & 63) * 4;
        float a = sAS[pl];
        f32x4 pk;
        #pragma unroll
        for (int u = 0; u < 4; ++u)
            pk[u] = 1.0f / (1.0f + __expf(-(a + sIF[i0 + u])));
        *(f32x4*)&out_resp[(p0 + pl) * IN + i0] = pk;
    }
}

extern "C" void kernel_launch(void* const* d_in, const int* in_sizes, int n_in,
                              void* d_out, int out_size, void* d_ws, size_t ws_size,
                              hipStream_t stream)
{
    const float* response     = (const float*)d_in[0];
    const int*   mask         = (const int*)d_in[1];
    const int*   item_index   = (const int*)d_in[2];
    const float* eps_ability  = (const float*)d_in[3];
    const float* eps_item     = (const float*)d_in[4];
    const float* w1           = (const float*)d_in[5];
    const float* b1           = (const float*)d_in[6];
    const float* w2           = (const float*)d_in[7];
    const float* b2           = (const float*)d_in[8];
    const float* w3           = (const float*)d_in[9];
    const float* b3           = (const float*)d_in[10];
    const float* w4           = (const float*)d_in[11];
    const float* b4           = (const float*)d_in[12];
    const float* mu_table     = (const float*)d_in[13];
    const float* logvar_table = (const float*)d_in[14];

    float* out = (float*)d_out;

    k_fused<<<PN / 16, 256, 0, stream>>>(
        response, mask, w1, b1, w2, b2, w3, b3, w4, b4,
        eps_ability, item_index, eps_item, mu_table, logvar_table,
        out + OFF_AMU, out + OFF_ALV, out + OFF_IMU, out + OFF_ILV,
        out + OFF_RESP);
}

// Round 8
// 98.793 us; speedup vs baseline: 1.4012x; 1.0108x over previous
//
#include <hip/hip_runtime.h>
#include <hip/hip_bf16.h>

// Problem constants
#define PN 4096
#define IN 256
#define HN 64
#define AN 32

// Output layout (FLOAT32 elements), reference return order:
// response_mu (P*I), ability_mu (P*A), ability_logvar (P*A), item_mu (I), item_logvar (I)
#define OFF_RESP 0
#define OFF_AMU  (PN * IN)
#define OFF_ALV  (OFF_AMU + PN * AN)
#define OFF_IMU  (OFF_ALV + PN * AN)
#define OFF_ILV  (OFF_IMU + IN)

// f(x) = elu( elu(x*w1+b1) @ w2 + b2 ) sampled on 128 grid points, x ∈ [0,1].
#define TROWS 128
#define PERS  8              // persons per block

typedef short  s16x8  __attribute__((ext_vector_type(8)));
typedef float  f32x4  __attribute__((ext_vector_type(4)));

__device__ __forceinline__ unsigned short f2bf(float f) {
    union { float f; unsigned int u; } v; v.f = f;
    unsigned int u = v.u;
    u += 0x7FFFu + ((u >> 16) & 1u);
    return (unsigned short)(u >> 16);
}

__device__ __forceinline__ float eluf(float x) {
    return x > 0.0f ? x : (__expf(x) - 1.0f);
}

__device__ __forceinline__ unsigned int pack_bf16(float a, float b) {
    union { __hip_bfloat162 h; unsigned int u; } cv;
    cv.h = __float22bfloat162_rn(make_float2(a, b));
    return cv.u;
}

// ---------------------------------------------------------------------------
// Fully fused kernel: 512 blocks x 256 threads, 8 persons/block, 2 blocks/CU.
//  1. build table T[128][64] = f(grid) via MFMA (all 4 waves on the elu fill)
//  2. scatter items into per-person weight rows W[8][128] (LDS f32 atomics;
//     one person per (wave,k) slice -> cnt needs no atomics, bins never
//     contend across waves)
//  3. hid_mean = (W @ T) / cnt              (MFMA, M=16 with 8 live rows)
//  4. t2 = elu(hid @ w3 + b3)               (MFMA)
//  5. out = t2 @ w4 + b4                    (MFMA)
//  6. amu/alv, abilitysum, item_feat, response sigmoid — all in-block.
// ---------------------------------------------------------------------------
__global__ __launch_bounds__(256, 2) void k_fused(
    const float* __restrict__ response,
    const int* __restrict__ mask,
    const float* __restrict__ w1,
    const float* __restrict__ b1,
    const float* __restrict__ w2,
    const float* __restrict__ b2,
    const float* __restrict__ w3,
    const float* __restrict__ b3,
    const float* __restrict__ w4,
    const float* __restrict__ b4,
    const float* __restrict__ eps_ability,
    const int* __restrict__ item_index,
    const float* __restrict__ eps_item,
    const float* __restrict__ mu_table,
    const float* __restrict__ logvar_table,
    float* __restrict__ out_amu,
    float* __restrict__ out_alv,
    float* __restrict__ out_imu,
    float* __restrict__ out_ilv,
    float* __restrict__ out_resp)
{
    // Region A (27648 B), time-multiplexed with barriers between roles:
    //   role 1: sH1[128][72]us (18432 B) + sW2T[64][72]us (9216 B)
    //   role 2: sTB[64][136]us (17408 B)   (table, B-operand layout)
    //   role 3: sHMB[16][72]us + sT2[16][72]us + sOut[16][68]f32
    __shared__ __align__(16) unsigned char sRegA[27648];
    __shared__ float sW[PERS * 132];                        // f32 scatter bins
    __shared__ __align__(16) unsigned short sWB[16 * 136];  // bf16 W, A-operand (rows 8..15 zero)
    __shared__ __align__(16) unsigned short sW3T[64 * 72];
    __shared__ __align__(16) unsigned short sW4T[64 * 72];
    __shared__ float sW1[64], sB1[64], sB2[64], sB3[64], sB4[64];
    __shared__ float sIF[256];
    __shared__ int   sCnt[16];
    __shared__ float sAS[PERS];

    unsigned short* sH1  = (unsigned short*)sRegA;              // [128][72]
    unsigned short* sW2T = (unsigned short*)sRegA + 128 * 72;   // [64][72]
    unsigned short* sTB  = (unsigned short*)sRegA;              // [64][136]
    unsigned short* sHMB = (unsigned short*)sRegA;              // [16][72]
    unsigned short* sT2  = (unsigned short*)sRegA + 16 * 72;    // [16][72]
    float*          sOut = (float*)(sRegA + 2 * 16 * 72 * 2);   // [16][68]

    const int t    = threadIdx.x;
    const int p0   = blockIdx.x * PERS;
    const int wave = t >> 6;
    const int lane = t & 63;
    const int quad = lane >> 4;
    const int r    = lane & 15;

    // ---- phase 1: stage weights/tables; zero bins ----
    if (t < 64) {
        sW1[t] = w1[t]; sB1[t] = b1[t]; sB2[t] = b2[t];
        sB3[t] = b3[t]; sB4[t] = b4[t];
    }
    for (int base = t * 4; base < 4096; base += 1024) {
        int j = base >> 6, n0 = base & 63;
        float4 v2 = *(const float4*)&w2[base];
        sW2T[(n0 + 0) * 72 + j] = f2bf(v2.x);
        sW2T[(n0 + 1) * 72 + j] = f2bf(v2.y);
        sW2T[(n0 + 2) * 72 + j] = f2bf(v2.z);
        sW2T[(n0 + 3) * 72 + j] = f2bf(v2.w);
        float4 v3 = *(const float4*)&w3[base];
        sW3T[(n0 + 0) * 72 + j] = f2bf(v3.x);
        sW3T[(n0 + 1) * 72 + j] = f2bf(v3.y);
        sW3T[(n0 + 2) * 72 + j] = f2bf(v3.z);
        sW3T[(n0 + 3) * 72 + j] = f2bf(v3.w);
        float4 v4 = *(const float4*)&w4[base];
        sW4T[(n0 + 0) * 72 + j] = f2bf(v4.x);
        sW4T[(n0 + 1) * 72 + j] = f2bf(v4.y);
        sW4T[(n0 + 2) * 72 + j] = f2bf(v4.z);
        sW4T[(n0 + 3) * 72 + j] = f2bf(v4.w);
    }
    {
        int idx = item_index[t];
        float mu = mu_table[idx];
        float lv = logvar_table[idx];
        sIF[t] = mu + eps_item[t] * __expf(0.5f * lv);
        if (blockIdx.x == 0) { out_imu[t] = mu; out_ilv[t] = lv; }
    }
    for (int idx = t; idx < PERS * 132; idx += 256) sW[idx] = 0.0f;
    for (int idx = t; idx < 16 * 68; idx += 256) ((unsigned int*)sWB)[idx] = 0u;
    if (t < 16) sCnt[t] = 0;
    __syncthreads();

    // ---- phase 2a: h1 grid rows (bf16), all 4 waves (2 threads per row) ----
    {
        int row  = t & 127;
        int half = t >> 7;               // 0/1 -> cols [0,32) / [32,64)
        float xg = (float)row * (1.0f / 127.0f);
        #pragma unroll
        for (int j0 = half * 32; j0 < half * 32 + 32; j0 += 8) {
            uint4 pk;
            pk.x = pack_bf16(eluf(fmaf(xg, sW1[j0+0], sB1[j0+0])),
                             eluf(fmaf(xg, sW1[j0+1], sB1[j0+1])));
            pk.y = pack_bf16(eluf(fmaf(xg, sW1[j0+2], sB1[j0+2])),
                             eluf(fmaf(xg, sW1[j0+3], sB1[j0+3])));
            pk.z = pack_bf16(eluf(fmaf(xg, sW1[j0+4], sB1[j0+4])),
                             eluf(fmaf(xg, sW1[j0+5], sB1[j0+5])));
            pk.w = pack_bf16(eluf(fmaf(xg, sW1[j0+6], sB1[j0+6])),
                             eluf(fmaf(xg, sW1[j0+7], sB1[j0+7])));
            *(uint4*)&sH1[row * 72 + j0] = pk;
        }
    }

    // ---- phase 2b: item scatter. (wave,k) slice = one person. ----
    #pragma unroll
    for (int k = 0; k < 2; ++k) {
        int vi = t + 256 * k;                         // 512 float4 = 8 persons x 256 items
        float4 xr = ((const float4*)(response + p0 * IN))[vi];
        int4   mr = ((const int4*)(mask + p0 * IN))[vi];
        int person = (t >> 6) + 4 * k;                // wave-uniform
        unsigned long long b0 = __ballot(mr.x != 0);
        unsigned long long b1 = __ballot(mr.y != 0);
        unsigned long long b2 = __ballot(mr.z != 0);
        unsigned long long b3 = __ballot(mr.w != 0);
        if (lane == 0)
            sCnt[person] = (int)(__popcll(b0) + __popcll(b1) + __popcll(b2) + __popcll(b3));
        float xs[4] = {xr.x, xr.y, xr.z, xr.w};
        int   ms[4] = {mr.x, mr.y, mr.z, mr.w};
        #pragma unroll
        for (int u = 0; u < 4; ++u) {
            if (ms[u]) {
                float kf = xs[u] * 127.0f;
                int kk = (int)kf;
                kk = (kk < 0) ? 0 : ((kk > 126) ? 126 : kk);
                float w = kf - (float)kk;
                atomicAdd(&sW[person * 132 + kk],     1.0f - w);
                atomicAdd(&sW[person * 132 + kk + 1], w);
            }
        }
    }
    __syncthreads();

    // ---- phase 3: table MFMA 128x64 @ 64x64 ; wave owns rows [32w,32w+32) ----
    f32x4 accT[2][4];
    #pragma unroll
    for (int rt = 0; rt < 2; ++rt)
        #pragma unroll
        for (int ct = 0; ct < 4; ++ct)
            accT[rt][ct] = (f32x4){0.f, 0.f, 0.f, 0.f};
    #pragma unroll
    for (int kk = 0; kk < 64; kk += 32) {
        s16x8 af[2], bfr[4];
        #pragma unroll
        for (int rt = 0; rt < 2; ++rt)
            af[rt] = *(const s16x8*)&sH1[(wave * 32 + rt * 16 + r) * 72 + kk + quad * 8];
        #pragma unroll
        for (int ct = 0; ct < 4; ++ct)
            bfr[ct] = *(const s16x8*)&sW2T[(ct * 16 + r) * 72 + kk + quad * 8];
        #pragma unroll
        for (int rt = 0; rt < 2; ++rt)
            #pragma unroll
            for (int ct = 0; ct < 4; ++ct)
                accT[rt][ct] = __builtin_amdgcn_mfma_f32_16x16x32_bf16(
                    af[rt], bfr[ct], accT[rt][ct], 0, 0, 0);
    }
    __syncthreads();   // all waves done reading sH1/sW2T

    // ---- phase 4: TB[col][k] = bf16(elu(acc+b2)) ; W -> bf16 WB (rows 0..7) ----
    #pragma unroll
    for (int ct = 0; ct < 4; ++ct) {
        int col = ct * 16 + r;
        float bb = sB2[col];
        #pragma unroll
        for (int rt = 0; rt < 2; ++rt)
            #pragma unroll
            for (int reg = 0; reg < 4; ++reg) {
                int krow = wave * 32 + rt * 16 + quad * 4 + reg;
                sTB[col * 136 + krow] = f2bf(eluf(accT[rt][ct][reg] + bb));
            }
    }
    #pragma unroll
    for (int idx = t; idx < PERS * 64; idx += 256) {  // 8 rows x 64 dword-pairs
        int row = idx >> 6, kp = (idx & 63) * 2;
        ((unsigned int*)sWB)[row * 68 + (idx & 63)] =
            pack_bf16(sW[row * 132 + kp], sW[row * 132 + kp + 1]);
    }
    __syncthreads();

    // ---- phase 5: hid = W(16x128,8 live) @ T(128x64) ; wave owns col-tile 16w ----
    f32x4 accH = (f32x4){0.f, 0.f, 0.f, 0.f};
    #pragma unroll
    for (int s = 0; s < 4; ++s) {
        s16x8 af = *(const s16x8*)&sWB[r * 136 + s * 32 + quad * 8];
        s16x8 bfr = *(const s16x8*)&sTB[(wave * 16 + r) * 136 + s * 32 + quad * 8];
        accH = __builtin_amdgcn_mfma_f32_16x16x32_bf16(af, bfr, accH, 0, 0, 0);
    }
    __syncthreads();   // all waves done reading sTB (region A reused below)

    // ---- phase 6: sHMB[person][col] = bf16(hid / max(cnt,1)) ----
    {
        int col = wave * 16 + r;
        #pragma unroll
        for (int reg = 0; reg < 4; ++reg) {
            int person = quad * 4 + reg;              // 0..15; rows 8..15 are junk, never stored
            float c = fmaxf((float)sCnt[person], 1.0f);
            sHMB[person * 72 + col] = f2bf(accH[reg] / c);
        }
    }
    __syncthreads();

    // ---- phase 7: t2 = elu(hid @ w3 + b3) ----
    f32x4 accA = (f32x4){0.f, 0.f, 0.f, 0.f};
    #pragma unroll
    for (int kk = 0; kk < 64; kk += 32) {
        s16x8 af = *(const s16x8*)&sHMB[r * 72 + kk + quad * 8];
        s16x8 bfr = *(const s16x8*)&sW3T[(wave * 16 + r) * 72 + kk + quad * 8];
        accA = __builtin_amdgcn_mfma_f32_16x16x32_bf16(af, bfr, accA, 0, 0, 0);
    }
    {
        int col = wave * 16 + r;
        float bb = sB3[col];
        #pragma unroll
        for (int reg = 0; reg < 4; ++reg)
            sT2[(quad * 4 + reg) * 72 + col] = f2bf(eluf(accA[reg] + bb));
    }
    __syncthreads();

    // ---- phase 8: out = t2 @ w4 + b4 -> sOut f32 ----
    f32x4 accB = (f32x4){0.f, 0.f, 0.f, 0.f};
    #pragma unroll
    for (int kk = 0; kk < 64; kk += 32) {
        s16x8 af = *(const s16x8*)&sT2[r * 72 + kk + quad * 8];
        s16x8 bfr = *(const s16x8*)&sW4T[(wave * 16 + r) * 72 + kk + quad * 8];
        accB = __builtin_amdgcn_mfma_f32_16x16x32_bf16(af, bfr, accB, 0, 0, 0);
    }
    {
        int col = wave * 16 + r;
        float bb = sB4[col];
        #pragma unroll
        for (int reg = 0; reg < 4; ++reg)
            sOut[(quad * 4 + reg) * 68 + col] = accB[reg] + bb;
    }
    __syncthreads();

    // ---- phase 9: amu/alv outputs + abilitysum (256 = 8 persons x 32) ----
    {
        int pl = t >> 5, a = t & 31;
        float mu = sOut[pl * 68 + a];
        float lv = sOut[pl * 68 + a + 32];
        out_amu[(p0 + pl) * AN + a] = mu;
        out_alv[(p0 + pl) * AN + a] = lv;
        float partial = mu + eps_ability[(p0 + pl) * AN + a] * __expf(0.5f * lv);
        #pragma unroll
        for (int off = 16; off; off >>= 1) partial += __shfl_xor(partial, off);
        if (a == 0) sAS[pl] = partial;
    }
    __syncthreads();

    // ---- phase 10: response sigmoid, 16B stores ----
    #pragma unroll
    for (int k3 = 0; k3 < 2; ++k3) {
        int vi = t + 256 * k3;               // 512 f32x4 = 8 persons x 256 items
        int pl = vi >> 6, i0 = (vi & 63) * 4;
        float a = sAS[pl];
        f32x4 pk;
        #pragma unroll
        for (int u = 0; u < 4; ++u)
            pk[u] = 1.0f / (1.0f + __expf(-(a + sIF[i0 + u])));
        *(f32x4*)&out_resp[(p0 + pl) * IN + i0] = pk;
    }
}

extern "C" void kernel_launch(void* const* d_in, const int* in_sizes, int n_in,
                              void* d_out, int out_size, void* d_ws, size_t ws_size,
                              hipStream_t stream)
{
    const float* response     = (const float*)d_in[0];
    const int*   mask         = (const int*)d_in[1];
    const int*   item_index   = (const int*)d_in[2];
    const float* eps_ability  = (const float*)d_in[3];
    const float* eps_item     = (const float*)d_in[4];
    const float* w1           = (const float*)d_in[5];
    const float* b1           = (const float*)d_in[6];
    const float* w2           = (const float*)d_in[7];
    const float* b2           = (const float*)d_in[8];
    const float* w3           = (const float*)d_in[9];
    const float* b3           = (const float*)d_in[10];
    const float* w4           = (const float*)d_in[11];
    const float* b4           = (const float*)d_in[12];
    const float* mu_table     = (const float*)d_in[13];
    const float* logvar_table = (const float*)d_in[14];

    float* out = (float*)d_out;

    k_fused<<<PN / PERS, 256, 0, stream>>>(
        response, mask, w1, b1, w2, b2, w3, b3, w4, b4,
        eps_ability, item_index, eps_item, mu_table, logvar_table,
        out + OFF_AMU, out + OFF_ALV, out + OFF_IMU, out + OFF_ILV,
        out + OFF_RESP);
}